// Round 7
// baseline (294.437 us; speedup 1.0000x reference)
//
#include <hip/hip_runtime.h>

typedef unsigned short u16;
typedef __attribute__((ext_vector_type(8))) short short8;
typedef __attribute__((ext_vector_type(4))) float f32x4;

constexpr int B_N    = 2;
constexpr int SEQ    = 1024;
constexpr int DMODEL = 768;
constexpr int DINNER = 1536;
constexpr int NH     = 24;
constexpr int DMLP   = 1920;
constexpr int NPROJ  = 6936;
constexpr int PP     = 7040;          // padded proj width (55*128)
constexpr int MROWS  = B_N * SEQ;     // 2048
constexpr int NCHUNK = 16;
constexpr int CLEN   = 64;

__device__ __forceinline__ u16 f2bf(float f) {
  union { float f; unsigned u; } x; x.f = f;
  unsigned r = x.u + 0x7fffu + ((x.u >> 16) & 1u);
  return (u16)(r >> 16);
}
__device__ __forceinline__ float bf2f(u16 b) {
  union { unsigned u; float f; } x; x.u = ((unsigned)b) << 16; return x.f;
}

__device__ __forceinline__ void gld_lds16(const u16* g, u16* l) {
  __builtin_amdgcn_global_load_lds((const __attribute__((address_space(1))) void*)g,
                                   (__attribute__((address_space(3))) void*)l, 16, 0, 0);
}

// swizzled bf16 fragment read: chunk cb (8 elems) of row, XOR-swizzled
__device__ __forceinline__ short8 frag(const u16* base, int row, int cb) {
  return *(const short8*)(base + row * 64 + ((cb ^ (row & 7)) << 3));
}
__device__ __forceinline__ int swz_idx(int row, int e) {
  return (((e >> 3) ^ (row & 7)) << 3) | (e & 7);
}

// ---------------- sizes -----------------------------------------------------
constexpr size_t E0  = (size_t)PP * DMODEL;
constexpr size_t E0s = (size_t)NPROJ * DMODEL;
constexpr size_t E1  = (size_t)DMODEL * DINNER;
constexpr size_t E2  = (size_t)DMLP * DMODEL;
constexpr size_t ETOT = E0 + E1 + 3 * E2;
constexpr int NCASTBLK = (int)((ETOT / 4 + 255) / 256);

// ---------------- rmsnorm body (shared by both call sites) ------------------
__device__ __forceinline__ void rmsnorm_body(
    int row, int t, const float* __restrict__ a, const float* __restrict__ b,
    const float* __restrict__ w, float* __restrict__ sum_out, u16* __restrict__ hout) {
  const float* pa = a + (size_t)row * DMODEL;
  const float* pb = b ? b + (size_t)row * DMODEL : nullptr;
  float v[3]; float ss = 0.f;
#pragma unroll
  for (int i = 0; i < 3; ++i) {
    int c = t + i * 256;
    float x = pa[c];
    if (pb) x += pb[c];
    v[i] = x; ss += x * x;
  }
#pragma unroll
  for (int o = 32; o > 0; o >>= 1) ss += __shfl_xor(ss, o);
  __shared__ float red[4];
  if ((t & 63) == 0) red[t >> 6] = ss;
  __syncthreads();
  ss = red[0] + red[1] + red[2] + red[3];
  float sc = rsqrtf(ss * (1.f / DMODEL) + 1e-5f);
#pragma unroll
  for (int i = 0; i < 3; ++i) {
    int c = t + i * 256;
    if (sum_out) sum_out[(size_t)row * DMODEL + c] = v[i];
    hout[(size_t)row * DMODEL + c] = f2bf(v[i] * sc * w[c]);
  }
}

// ---------------- merged: weight casts + rmsnorm1 ---------------------------
__global__ __launch_bounds__(256) void cast_norm_kernel(
    const float* __restrict__ w_in, const float* __restrict__ w_out,
    const float* __restrict__ w_g, const float* __restrict__ w_u,
    const float* __restrict__ w_d,
    u16* __restrict__ wb_in, u16* __restrict__ wb_out,
    u16* __restrict__ wb_gu, u16* __restrict__ wb_d,
    const float* __restrict__ x, const float* __restrict__ n1w,
    u16* __restrict__ h1) {
  if (blockIdx.x >= NCASTBLK) {
    rmsnorm_body(blockIdx.x - NCASTBLK, threadIdx.x, x, nullptr, n1w, nullptr, h1);
    return;
  }
  size_t i = ((size_t)blockIdx.x * 256 + threadIdx.x) * 4;
  if (i >= ETOT) return;
  float4 v; u16* dst;
  if (i < E0) {
    dst = wb_in + i;
    if (i < E0s) v = *(const float4*)(w_in + i);
    else { v.x = v.y = v.z = v.w = 0.f; }
  } else if (i < E0 + E1) {
    size_t k = i - E0; dst = wb_out + k; v = *(const float4*)(w_out + k);
  } else if (i < E0 + E1 + 2 * E2) {
    size_t k = i - E0 - E1;
    size_t r = k / DMODEL, col = k - r * DMODEL;
    const float* src = (r & 1) ? w_u : w_g;
    v = *(const float4*)(src + (r >> 1) * DMODEL + col);
    dst = wb_gu + k;
  } else {
    size_t k = i - E0 - E1 - 2 * E2; dst = wb_d + k; v = *(const float4*)(w_d + k);
  }
  short4 o;
  o.x = (short)f2bf(v.x); o.y = (short)f2bf(v.y);
  o.z = (short)f2bf(v.z); o.w = (short)f2bf(v.w);
  *(short4*)dst = o;
}

// ---------------- fused (a + b) -> rmsnorm -> bf16 ; raw-sum out ------------
__global__ __launch_bounds__(256) void add_rmsnorm_kernel(
    const float* __restrict__ a, const float* __restrict__ b,
    const float* __restrict__ w, float* __restrict__ sum_out,
    u16* __restrict__ hout) {
  rmsnorm_body(blockIdx.x, threadIdx.x, a, b, w, sum_out, hout);
}

// ---------------- bf16 MFMA GEMM: C = A * B^T --------------------------------
// 2-phase stage-ahead double-buffer (T3-lite): STAGE(next) || compute(cur),
// one barrier per K-step. T2 swizzle via pre-swizzled global source.
// MODE 0: f32 out (+optional addsrc). MODE 1: bf16 out. MODE 2: glu-paired.
template<int BM, int BN, int MODE>
__global__ __launch_bounds__(256) void gemm_bt_kernel(
    const u16* __restrict__ A, const u16* __restrict__ Bw,
    void* __restrict__ Cv, int K, int ldc, const float* __restrict__ addsrc) {
  constexpr int MI = BM / 32;
  constexpr int NJ = BN / 32;
  constexpr int ASZ = BM * 64;
  constexpr int BSZ = BN * 64;
  __shared__ u16 As[2 * ASZ];
  __shared__ u16 Bs[2 * BSZ];
  const int t = threadIdx.x;
  const int lane = t & 63;
  const int wave = t >> 6;
  const int wm = wave >> 1, wn = wave & 1;
  const int gx = gridDim.x, gy = gridDim.y;
  const int o = blockIdx.y * gx + blockIdx.x;
  const int nwg = gx * gy;
  const int cid = (o & 7) * (nwg >> 3) + (o >> 3);
  const int bx = cid / gy, by = cid - bx * gy;
  const int m0 = by * BM, n0 = bx * BN;
  f32x4 acc[MI][NJ] = {};
  const int rr = t >> 3;
  const int kc = (((t & 7) ^ (rr & 7))) * 8;     // inverse-swizzled source chunk
  const u16* ga = A + (size_t)(m0 + rr) * K + kc;
  const u16* gb = Bw + (size_t)(n0 + rr) * K + kc;
  // prologue: stage kt=0 into buffer 0
#pragma unroll
  for (int i = 0; i < MI; ++i)
    gld_lds16(ga + (size_t)i * 32 * K, As + i * 2048 + t * 8);
#pragma unroll
  for (int i = 0; i < NJ; ++i)
    gld_lds16(gb + (size_t)i * 32 * K, Bs + i * 2048 + t * 8);
  __syncthreads();
  int cur = 0;
  for (int kt = 0; kt < K; kt += 64) {
    const int nxt = cur ^ 1;
    if (kt + 64 < K) {   // stage next tile while computing current
#pragma unroll
      for (int i = 0; i < MI; ++i)
        gld_lds16(ga + (size_t)i * 32 * K + kt + 64, As + nxt * ASZ + i * 2048 + t * 8);
#pragma unroll
      for (int i = 0; i < NJ; ++i)
        gld_lds16(gb + (size_t)i * 32 * K + kt + 64, Bs + nxt * BSZ + i * 2048 + t * 8);
    }
    const u16* ab = As + cur * ASZ;
    const u16* bb = Bs + cur * BSZ;
#pragma unroll
    for (int kh = 0; kh < 2; ++kh) {
      const int cq = kh * 4 + (lane >> 4);
      short8 af[MI], bfr[NJ];
#pragma unroll
      for (int i = 0; i < MI; ++i)
        af[i] = frag(ab, wm * (BM / 2) + i * 16 + (lane & 15), cq);
#pragma unroll
      for (int j = 0; j < NJ; ++j)
        bfr[j] = frag(bb, wn * (BN / 2) + j * 16 + (lane & 15), cq);
#pragma unroll
      for (int i = 0; i < MI; ++i)
#pragma unroll
        for (int j = 0; j < NJ; ++j)
          acc[i][j] = __builtin_amdgcn_mfma_f32_16x16x32_bf16(af[i], bfr[j], acc[i][j], 0, 0, 0);
    }
    __syncthreads();     // drains stage (vmcnt) + read completion
    cur = nxt;
  }
  const int cr = (lane >> 4) * 4;
  const int cc = lane & 15;
#pragma unroll
  for (int i = 0; i < MI; ++i) {
#pragma unroll
    for (int j = 0; j < NJ; ++j) {
      int row = m0 + wm * (BM / 2) + i * 16 + cr;
      int col = n0 + wn * (BN / 2) + j * 16 + cc;
      if (MODE == 0) {
        float* C = (float*)Cv;
        float* cp = C + (size_t)row * ldc + col;
        if (addsrc) {
          const float* ap = addsrc + (size_t)row * ldc + col;
#pragma unroll
          for (int r = 0; r < 4; ++r) cp[(size_t)r * ldc] = acc[i][j][r] + ap[(size_t)r * ldc];
        } else {
#pragma unroll
          for (int r = 0; r < 4; ++r) cp[(size_t)r * ldc] = acc[i][j][r];
        }
      } else if (MODE == 1) {
        u16* C = (u16*)Cv;
#pragma unroll
        for (int r = 0; r < 4; ++r)
          C[(size_t)(row + r) * ldc + col] = f2bf(acc[i][j][r]);
      } else {
        u16* C = (u16*)Cv;
#pragma unroll
        for (int r = 0; r < 4; ++r) {
          float v = acc[i][j][r];
          float p = __shfl_xor(v, 1);
          if ((lane & 1) == 0) {
            float g = v, u = p;
            float res = g / (1.f + __expf(-g)) * u;
            C[(size_t)(row + r) * ldc + (col >> 1)] = f2bf(res);
          }
        }
      }
    }
  }
}

// ---------------- prep: B/C rmsnorm+bias (in place, bf16), A=log(alpha),
//                  skip, dtheta, pre-scale x_ssm by gamma. One wave/(m,h). --
__global__ __launch_bounds__(256) void prep_kernel(
    u16* __restrict__ proj, const float* __restrict__ A_log,
    const float* __restrict__ Dv, const float* __restrict__ dt_bias,
    const float* __restrict__ B_bias, const float* __restrict__ C_bias,
    const float* __restrict__ Bnw, const float* __restrict__ Cnw,
    float* __restrict__ Abuf, float* __restrict__ skip_b,
    float* __restrict__ dtheta) {
  int wid = blockIdx.x * 4 + (threadIdx.x >> 6);
  int lane = threadIdx.x & 63;
  int m = wid / NH, h = wid - m * NH;
  u16* row = proj + (size_t)m * PP;

  float Braw = bf2f(row[3072 + h * 64 + lane]);
  float Craw = bf2f(row[4608 + h * 64 + lane]);
  float sb = Braw * Braw, sc2 = Craw * Craw;
#pragma unroll
  for (int o = 32; o > 0; o >>= 1) { sb += __shfl_xor(sb, o); sc2 += __shfl_xor(sc2, o); }
  float rb = rsqrtf(sb * (1.f / 64.f) + 1e-5f);
  float rc = rsqrtf(sc2 * (1.f / 64.f) + 1e-5f);
  row[3072 + h * 64 + lane] = f2bf(Braw * rb * Bnw[lane] + B_bias[h * 64 + lane]);
  row[4608 + h * 64 + lane] = f2bf(Craw * rc * Cnw[lane] + C_bias[h * 64 + lane]);

  float dtr = bf2f(row[6144 + h]) + dt_bias[h];
  float dt = dtr > 20.f ? dtr : log1pf(__expf(dtr));
  float A = -__expf(A_log[h]) * dt;
  float alpha = __expf(A);
  float gamma = (alpha - 1.f) / (A + 1e-6f) * 0.5f + 1.f;

  float xv = bf2f(row[1536 + h * 64 + lane]);
  float sx = xv;
#pragma unroll
  for (int o = 32; o > 0; o >>= 1) sx += __shfl_xor(sx, o);
  row[1536 + h * 64 + lane] = f2bf(xv * gamma);   // pre-scale for scan

  if (lane == 0) {
    Abuf[(size_t)m * NH + h] = A;           // log(alpha)
    skip_b[(size_t)m * NH + h] = Dv[h] * sx;
  }
  if (lane < 32) {
    float th = bf2f(row[6168 + h * 32 + lane]);
    dtheta[(size_t)m * 768 + h * 32 + lane] = dt * th;
  }
}

// ---------------- chunked cumsum of dtheta over s ---------------------------
__global__ __launch_bounds__(256) void cumsum_a_kernel(float* __restrict__ dtheta,
                                                       float* __restrict__ ctot) {
  int bid = blockIdx.x;                  // 96 = 2 * 16 * 3
  int cb = bid % 3, rest = bid / 3;
  int c = rest & 15, b = rest >> 4;
  int col = cb * 256 + threadIdx.x;
  float* p = dtheta + ((size_t)(b * SEQ + c * CLEN)) * 768 + col;
  float acc = 0.f;
#pragma unroll 4
  for (int s = 0; s < CLEN; ++s) {
    acc += p[(size_t)s * 768];
    p[(size_t)s * 768] = acc;
  }
  ctot[((size_t)b * NCHUNK + c) * 768 + col] = acc;
}

__global__ void cumsum_b_kernel(float* __restrict__ ctot) {
  int tid = blockIdx.x * 256 + threadIdx.x;   // < 1536
  int b = tid / 768, col = tid - b * 768;
  float pre = 0.f;
#pragma unroll
  for (int c = 0; c < NCHUNK; ++c) {
    size_t o = ((size_t)b * NCHUNK + c) * 768 + col;
    float v = ctot[o];
    ctot[o] = pre;
    pre += v;
  }
}

// ---------------- rope: rotate B and C pairs in place (bf16) ---------------
__global__ __launch_bounds__(256) void rope_kernel(
    u16* __restrict__ proj, const float* __restrict__ dtheta,
    const float* __restrict__ ctot) {
  int wid = blockIdx.x * 4 + (threadIdx.x >> 6);
  int lane = threadIdx.x & 63;
  int m = wid / NH, h = wid - m * NH;
  int j = lane & 31;
  int b = m >> 10;
  int c = (m >> 6) & 15;
  float ang = dtheta[(size_t)m * 768 + h * 32 + j] +
              ctot[((size_t)b * NCHUNK + c) * 768 + h * 32 + j];
  float sn, cs;
  __sincosf(ang, &sn, &cs);
  int base = (lane < 32) ? 3072 : 4608;
  unsigned* p = (unsigned*)(proj + (size_t)m * PP + base + h * 64) + j;
  unsigned v = *p;
  float x1 = bf2f((u16)(v & 0xffffu));
  float x2 = bf2f((u16)(v >> 16));
  *p = (unsigned)f2bf(cs * x1 - sn * x2) | ((unsigned)f2bf(sn * x1 + cs * x2) << 16);
}

// ---------------- scan kernel A: per (bh, chunk):
//   L prefix; G = C.B^T (direct-global frags); Gm = mask/decay(G);
//   Y1 = Gm @ xs ; H_out = xs^T . (ratio*B). Writes Lbuf, Hbuf, y1b. --------
__global__ __launch_bounds__(256) void scanA_kernel(
    const u16* __restrict__ proj, const float* __restrict__ Abuf,
    float* __restrict__ Lbuf, float* __restrict__ Hbuf,
    float* __restrict__ y1b) {
  int c = blockIdx.x & 15, bh = blockIdx.x >> 4;
  int b = bh / NH, h = bh - b * NH;
  int t = threadIdx.x, w = t >> 6, l = t & 63;
  __shared__ float sTmp[64][65];
  __shared__ u16 sBT[64 * 64];   // (ratio*B)^T : [n][t]
  __shared__ u16 sXT[64 * 64];   // xs^T : [p][t]
  __shared__ u16 sGm[64 * 64];   // masked decayed G : [s][t]
  __shared__ float sRatio[64], sL[64];
  int m0 = b * SEQ + c * CLEN;
  if (w == 0) {
    float v = Abuf[(size_t)(m0 + l) * NH + h];
#pragma unroll
    for (int o = 1; o < 64; o <<= 1) {
      float u = __shfl_up(v, o);
      if (l >= o) v += u;
    }
    Lbuf[(size_t)(m0 + l) * NH + h] = v;
    sL[l] = v;
    float L63 = __shfl(v, 63);
    sRatio[l] = __expf(L63 - v);
  }
  int rr = t >> 2, q = t & 3;
  {  // stage rope'd B -> sTmp (f32)
    const u16* row = proj + (size_t)(m0 + rr) * PP + 3072 + h * 64;
#pragma unroll
    for (int k = 0; k < 4; ++k) {
      int e = q * 16 + k * 4;
      short4 sv = *(const short4*)(row + e);
      float4 ov;
      ov.x = bf2f((u16)sv.x); ov.y = bf2f((u16)sv.y);
      ov.z = bf2f((u16)sv.z); ov.w = bf2f((u16)sv.w);
      *(float4*)&sTmp[rr][e] = ov;
    }
  }
  // direct-global fragment loads for G = C . B^T
  const u16* baseC = proj + (size_t)m0 * PP + 4608 + h * 64;
  const u16* baseB = proj + (size_t)m0 * PP + 3072 + h * 64;
  short8 cf[2], bgf[2][4];
#pragma unroll
  for (int kh = 0; kh < 2; ++kh) {
    int cq = kh * 4 + (l >> 4);
    cf[kh] = *(const short8*)(baseC + (size_t)(w * 16 + (l & 15)) * PP + cq * 8);
#pragma unroll
    for (int j = 0; j < 4; ++j)
      bgf[kh][j] = *(const short8*)(baseB + (size_t)(j * 16 + (l & 15)) * PP + cq * 8);
  }
  __syncthreads();          // sTmp(B), sRatio, sL ready
  f32x4 g4[4] = {};
#pragma unroll
  for (int kh = 0; kh < 2; ++kh)
#pragma unroll
    for (int j = 0; j < 4; ++j)
      g4[j] = __builtin_amdgcn_mfma_f32_16x16x32_bf16(cf[kh], bgf[kh][j], g4[j], 0, 0, 0);
  {  // transpose + ratio-scale -> sBT[n][t]
#pragma unroll
    for (int k = 0; k < 8; ++k) {
      int tw = (l + w * 8 + k) & 31;
      int t0 = tw * 2;
      float v0 = sTmp[t0][l] * sRatio[t0];
      float v1 = sTmp[t0 + 1][l] * sRatio[t0 + 1];
      unsigned pk = (unsigned)f2bf(v0) | ((unsigned)f2bf(v1) << 16);
      *(unsigned*)(sBT + l * 64 + swz_idx(l, t0)) = pk;
    }
  }
  __syncthreads();          // sTmp consumed
  {  // stage xs -> sTmp
    const u16* row = proj + (size_t)(m0 + rr) * PP + 1536 + h * 64;
#pragma unroll
    for (int k = 0; k < 4; ++k) {
      int e = q * 16 + k * 4;
      short4 sv = *(const short4*)(row + e);
      float4 ov;
      ov.x = bf2f((u16)sv.x); ov.y = bf2f((u16)sv.y);
      ov.z = bf2f((u16)sv.z); ov.w = bf2f((u16)sv.w);
      *(float4*)&sTmp[rr][e] = ov;
    }
  }
  __syncthreads();
  {  // transpose -> sXT[p][t] (raw)
#pragma unroll
    for (int k = 0; k < 8; ++k) {
      int tw = (l + w * 8 + k) & 31;
      int t0 = tw * 2;
      unsigned pk = (unsigned)f2bf(sTmp[t0][l]) | ((unsigned)f2bf(sTmp[t0 + 1][l]) << 16);
      *(unsigned*)(sXT + l * 64 + swz_idx(l, t0)) = pk;
    }
  }
  {  // mask + decay -> sGm
    int sr = w * 16 + ((l >> 4) << 2);
#pragma unroll
    for (int j = 0; j < 4; ++j) {
      int tc = j * 16 + (l & 15);
#pragma unroll
      for (int r = 0; r < 4; ++r) {
        int s = sr + r;
        float gv = (tc <= s) ? g4[j][r] * __expf(sL[s] - sL[tc]) : 0.f;
        sGm[s * 64 + swz_idx(s, tc)] = f2bf(gv);
      }
    }
  }
  __syncthreads();          // sXT + sGm ready
  // Y1[s][p] = Gm @ xs ; Hout[p][n] = xs^T . (ratio*B)
  f32x4 y1[4] = {}, ho[4] = {};
#pragma unroll
  for (int kh = 0; kh < 2; ++kh) {
    int cq = kh * 4 + (l >> 4);
    short8 agm = frag(sGm, w * 16 + (l & 15), cq);
    short8 axt = frag(sXT, w * 16 + (l & 15), cq);
#pragma unroll
    for (int j = 0; j < 4; ++j) {
      y1[j] = __builtin_amdgcn_mfma_f32_16x16x32_bf16(agm, frag(sXT, j * 16 + (l & 15), cq), y1[j], 0, 0, 0);
      ho[j] = __builtin_amdgcn_mfma_f32_16x16x32_bf16(axt, frag(sBT, j * 16 + (l & 15), cq), ho[j], 0, 0, 0);
    }
  }
  float* Hp = Hbuf + ((size_t)(bh * NCHUNK + c)) * 4096;
  int pr = w * 16 + ((l >> 4) << 2);
#pragma unroll
  for (int j = 0; j < 4; ++j)
#pragma unroll
    for (int r = 0; r < 4; ++r)
      Hp[(size_t)(pr + r) * 64 + j * 16 + (l & 15)] = ho[j][r];
#pragma unroll
  for (int r = 0; r < 4; ++r) {
    int s = pr + r;
#pragma unroll
    for (int j = 0; j < 4; ++j)
      y1b[(size_t)(m0 + s) * DINNER + h * 64 + j * 16 + (l & 15)] = y1[j][r];
  }
}

// ---------------- scan phase 2: element-parallel chunk recurrence ----------
__global__ __launch_bounds__(256) void scan2_kernel(
    float* __restrict__ Hbuf, const float* __restrict__ Lbuf) {
  int bh = blockIdx.x >> 4;
  int e = (blockIdx.x & 15) * 256 + threadIdx.x;
  int b = bh / NH, h = bh - b * NH;
  float S = 0.f;
  for (int c = 0; c < NCHUNK; ++c) {
    float* Hp = Hbuf + ((size_t)(bh * NCHUNK + c)) * 4096 + e;
    float P = __expf(Lbuf[(size_t)(b * SEQ + c * CLEN + CLEN - 1) * NH + h]);
    float v = *Hp;
    *Hp = S;
    S = P * S + v;
  }
}

// ---------------- scan kernel B: Y2 = C @ Hin^T (direct-global frags);
//   y = y1 + e^L * y2 + skip ; * silu(z) -> actb (bf16) ---------------------
__global__ __launch_bounds__(256) void scanB_kernel(
    const u16* __restrict__ proj, const float* __restrict__ Hbuf,
    const float* __restrict__ Lbuf, const float* __restrict__ skip_b,
    const float* __restrict__ y1b, u16* __restrict__ actb) {
  int c = blockIdx.x & 15, bh = blockIdx.x >> 4;
  int b = bh / NH, h = bh - b * NH;
  int t = threadIdx.x, w = t >> 6, l = t & 63;
  __shared__ float sL[64], sSkip[64];
  int m0 = b * SEQ + c * CLEN;
  if (w == 0) {
    sL[l] = Lbuf[(size_t)(m0 + l) * NH + h];
    sSkip[l] = skip_b[(size_t)(m0 + l) * NH + h];
  }
  const u16* baseC = proj + (size_t)m0 * PP + 4608 + h * 64;
  const float* Hp = Hbuf + ((size_t)(bh * NCHUNK + c)) * 4096;
  short8 cf[2], hf[2][4];
#pragma unroll
  for (int kh = 0; kh < 2; ++kh) {
    int cq = kh * 4 + (l >> 4);
    cf[kh] = *(const short8*)(baseC + (size_t)(w * 16 + (l & 15)) * PP + cq * 8);
#pragma unroll
    for (int j = 0; j < 4; ++j) {
      const float* hp = Hp + (size_t)(j * 16 + (l & 15)) * 64 + cq * 8;
      float4 a = *(const float4*)hp;
      float4 b2 = *(const float4*)(hp + 4);
      short8 hv;
      hv[0] = (short)f2bf(a.x);  hv[1] = (short)f2bf(a.y);
      hv[2] = (short)f2bf(a.z);  hv[3] = (short)f2bf(a.w);
      hv[4] = (short)f2bf(b2.x); hv[5] = (short)f2bf(b2.y);
      hv[6] = (short)f2bf(b2.z); hv[7] = (short)f2bf(b2.w);
      hf[kh][j] = hv;
    }
  }
  __syncthreads();
  f32x4 y2[4] = {};
#pragma unroll
  for (int kh = 0; kh < 2; ++kh)
#pragma unroll
    for (int j = 0; j < 4; ++j)
      y2[j] = __builtin_amdgcn_mfma_f32_16x16x32_bf16(cf[kh], hf[kh][j], y2[j], 0, 0, 0);
  int sr = w * 16 + ((l >> 4) << 2);
#pragma unroll
  for (int r = 0; r < 4; ++r) {
    int s = sr + r;
    float scale = __expf(sL[s]);
    float skp = sSkip[s];
    size_t mrow = (size_t)(m0 + s);
#pragma unroll
    for (int j = 0; j < 4; ++j) {
      int p = j * 16 + (l & 15);
      float y = y1b[mrow * DINNER + h * 64 + p] + scale * y2[j][r] + skp;
      float z = bf2f(proj[mrow * PP + h * 64 + p]);
      float sg = 1.f / (1.f + __expf(-z));
      actb[mrow * DINNER + h * 64 + p] = f2bf(y * z * sg);
    }
  }
}

extern "C" void kernel_launch(void* const* d_in, const int* in_sizes, int n_in,
                              void* d_out, int out_size, void* d_ws, size_t ws_size,
                              hipStream_t stream) {
  (void)in_sizes; (void)n_in; (void)out_size; (void)ws_size;
  const float* x      = (const float*)d_in[0];
  const float* n1w    = (const float*)d_in[1];
  const float* n2w    = (const float*)d_in[2];
  const float* w_in   = (const float*)d_in[3];
  const float* w_out  = (const float*)d_in[4];
  const float* A_log  = (const float*)d_in[5];
  const float* Dv     = (const float*)d_in[6];
  const float* dt_b   = (const float*)d_in[7];
  const float* B_bias = (const float*)d_in[8];
  const float* C_bias = (const float*)d_in[9];
  const float* Bnw    = (const float*)d_in[10];
  const float* Cnw    = (const float*)d_in[11];
  const float* w_g    = (const float*)d_in[12];
  const float* w_u    = (const float*)d_in[13];
  const float* w_d    = (const float*)d_in[14];
  float* out = (float*)d_out;

  char* ws = (char*)d_ws;
  size_t off = 0;
  auto alloc = [&](size_t bytes) -> char* {
    char* p = ws + off;
    off = (off + bytes + 255) & ~(size_t)255;
    return p;
  };
  u16*   wb_in  = (u16*)  alloc(E0 * 2);
  u16*   wb_out = (u16*)  alloc(E1 * 2);
  u16*   wb_gu  = (u16*)  alloc(E2 * 2 * 2);      // interleaved gate/up rows
  u16*   wb_d   = (u16*)  alloc(E2 * 2);
  u16*   h1     = (u16*)  alloc((size_t)MROWS * DMODEL * 2);
  u16*   proj   = (u16*)  alloc((size_t)MROWS * PP * 2);
  float* Abuf   = (float*)alloc((size_t)MROWS * NH * 4);
  float* skip_b = (float*)alloc((size_t)MROWS * NH * 4);
  float* Lbuf   = (float*)alloc((size_t)MROWS * NH * 4);
  float* dtheta = (float*)alloc((size_t)MROWS * 768 * 4);
  float* ctot   = (float*)alloc((size_t)B_N * NCHUNK * 768 * 4);
  float* Hbuf   = (float*)alloc((size_t)B_N * NH * NCHUNK * 4096 * 4);
  float* y1b    = (float*)alloc((size_t)MROWS * DINNER * 4);
  u16*   actb   = (u16*)  alloc((size_t)MROWS * DINNER * 2);
  float* tmp1   = (float*)alloc((size_t)MROWS * DMODEL * 4);
  float* x2     = (float*)alloc((size_t)MROWS * DMODEL * 4);
  u16*   h2     = (u16*)  alloc((size_t)MROWS * DMODEL * 2);
  u16*   gub    = (u16*)  alloc((size_t)MROWS * DMLP * 2);

  // 1. weight casts + rmsnorm1 in one launch
  cast_norm_kernel<<<NCASTBLK + MROWS, 256, 0, stream>>>(
      w_in, w_out, w_g, w_u, w_d, wb_in, wb_out, wb_gu, wb_d, x, n1w, h1);
  {  // in_proj -> proj (bf16): 55 x 32 = 1760 blocks
    dim3 g(PP / 128, MROWS / 64);
    gemm_bt_kernel<64, 128, 1><<<g, 256, 0, stream>>>(h1, wb_in, proj, DMODEL, PP, nullptr);
  }
  prep_kernel<<<MROWS * NH / 4, 256, 0, stream>>>(proj, A_log, Dv, dt_b, B_bias, C_bias,
                                                  Bnw, Cnw, Abuf, skip_b, dtheta);
  cumsum_a_kernel<<<B_N * NCHUNK * 3, 256, 0, stream>>>(dtheta, ctot);
  cumsum_b_kernel<<<6, 256, 0, stream>>>(ctot);
  rope_kernel<<<MROWS * NH / 4, 256, 0, stream>>>(proj, dtheta, ctot);
  scanA_kernel<<<B_N * NH * NCHUNK, 256, 0, stream>>>(proj, Abuf, Lbuf, Hbuf, y1b);
  scan2_kernel<<<B_N * NH * NCHUNK, 256, 0, stream>>>(Hbuf, Lbuf);
  scanB_kernel<<<B_N * NH * NCHUNK, 256, 0, stream>>>(proj, Hbuf, Lbuf, skip_b, y1b, actb);
  {  // out_proj -> tmp1 (f32): 12 x 32 = 384 blocks
    dim3 g(DMODEL / 64, MROWS / 64);
    gemm_bt_kernel<64, 64, 0><<<g, 256, 0, stream>>>(actb, wb_out, tmp1, DINNER, DMODEL, nullptr);
  }
  add_rmsnorm_kernel<<<MROWS, 256, 0, stream>>>(x, tmp1, n2w, x2, h2);
  {  // gate+up fused GLU -> gub (bf16): 30 x 32 = 960 blocks
    dim3 g(2 * DMLP / 128, MROWS / 64);
    gemm_bt_kernel<64, 128, 2><<<g, 256, 0, stream>>>(h2, wb_gu, gub, DMODEL, DMLP, nullptr);
  }
  {  // down + residual -> out: 12 x 32 = 384 blocks
    dim3 g(DMODEL / 64, MROWS / 64);
    gemm_bt_kernel<64, 64, 0><<<g, 256, 0, stream>>>(gub, wb_d, out, DMLP, DMODEL, x2);
  }
}